// Round 1
// baseline (749.168 us; speedup 1.0000x reference)
//
#include <hip/hip_runtime.h>
#include <hip/hip_bf16.h>
#include <cmath>
#include <cstdint>

typedef __attribute__((ext_vector_type(8))) short short8;
typedef __attribute__((ext_vector_type(4))) float floatx4;
typedef __attribute__((ext_vector_type(4))) unsigned int uintx4;

__device__ inline unsigned short f2bf(float f) {
  unsigned int u = __builtin_bit_cast(unsigned int, f);
  unsigned int r = (u + 0x7FFFu + ((u >> 16) & 1u)) >> 16;
  return (unsigned short)r;
}
__device__ inline float bf2f(unsigned short h) {
  unsigned int u = ((unsigned int)h) << 16;
  return __builtin_bit_cast(float, u);
}

// ---------------- elementwise fp32 -> bf16 (float4 loads) ----------------
__global__ void k_f32_to_bf16(const float* __restrict__ in, unsigned short* __restrict__ out, int n4) {
  int i = blockIdx.x * 256 + threadIdx.x;
  if (i >= n4) return;
  float4 v = reinterpret_cast<const float4*>(in)[i];
  uint2 o;
  o.x = (unsigned)f2bf(v.x) | ((unsigned)f2bf(v.y) << 16);
  o.y = (unsigned)f2bf(v.z) | ((unsigned)f2bf(v.w) << 16);
  reinterpret_cast<uint2*>(out)[i] = o;
}

// ---------------- transpose + convert: fp32 [K][N] -> bf16 [N][K] ----------------
__global__ void k_transpose_w(const float* __restrict__ in, unsigned short* __restrict__ out, int K, int N) {
  __shared__ float t[32][33];
  int n0 = blockIdx.x * 32, k0 = blockIdx.y * 32;
  int tx = threadIdx.x & 31, ty = threadIdx.x >> 5; // 256 threads: ty 0..7
  #pragma unroll
  for (int r = ty; r < 32; r += 8)
    t[r][tx] = in[(long)(k0 + r) * N + n0 + tx];
  __syncthreads();
  #pragma unroll
  for (int r = ty; r < 32; r += 8)
    out[(long)(n0 + r) * K + k0 + tx] = f2bf(t[tx][r]);
}

// ---------------- small fp32 GEMM: out[d][0..3] = W[d,:] @ Ws (Kw x 4) ----------------
__global__ void k_wproj(const float* __restrict__ W, const float* __restrict__ Ws,
                        float* __restrict__ out, int Kw) {
  int d = blockIdx.x;
  float a0 = 0, a1 = 0, a2 = 0, a3 = 0;
  for (int j = threadIdx.x; j < Kw; j += 256) {
    float w = W[(long)d * Kw + j];
    float4 g = reinterpret_cast<const float4*>(Ws)[j];
    a0 += w * g.x; a1 += w * g.y; a2 += w * g.z; a3 += w * g.w;
  }
  #pragma unroll
  for (int off = 1; off < 64; off <<= 1) {
    a0 += __shfl_xor(a0, off, 64); a1 += __shfl_xor(a1, off, 64);
    a2 += __shfl_xor(a2, off, 64); a3 += __shfl_xor(a3, off, 64);
  }
  __shared__ float red[4][4];
  if ((threadIdx.x & 63) == 0) {
    int wv = threadIdx.x >> 6;
    red[wv][0] = a0; red[wv][1] = a1; red[wv][2] = a2; red[wv][3] = a3;
  }
  __syncthreads();
  if (threadIdx.x < 4) {
    int nn = threadIdx.x;
    out[d * 4 + nn] = red[0][nn] + red[1][nn] + red[2][nn] + red[3][nn];
  }
}

// ---------------- bias: fp32 gate/delta -> bias[(b*4+n)*S + s] ----------------
__global__ void k_bias(const float* __restrict__ hs, const float* __restrict__ Wqg,
                       const float* __restrict__ Wvd, float* __restrict__ bias) {
  int row = blockIdx.x;           // b*2048 + s
  int b = row >> 11, s = row & 2047;
  float g0 = 0, g1 = 0, g2 = 0, g3 = 0, d0 = 0, d1 = 0, d2 = 0, d3 = 0;
  const float* h = hs + (long)row * 2048;
  for (int j = threadIdx.x; j < 2048; j += 256) {
    float x = h[j];
    float4 a = reinterpret_cast<const float4*>(Wqg)[j];
    float4 c = reinterpret_cast<const float4*>(Wvd)[j];
    g0 += x * a.x; g1 += x * a.y; g2 += x * a.z; g3 += x * a.w;
    d0 += x * c.x; d1 += x * c.y; d2 += x * c.z; d3 += x * c.w;
  }
  #pragma unroll
  for (int off = 1; off < 64; off <<= 1) {
    g0 += __shfl_xor(g0, off, 64); g1 += __shfl_xor(g1, off, 64);
    g2 += __shfl_xor(g2, off, 64); g3 += __shfl_xor(g3, off, 64);
    d0 += __shfl_xor(d0, off, 64); d1 += __shfl_xor(d1, off, 64);
    d2 += __shfl_xor(d2, off, 64); d3 += __shfl_xor(d3, off, 64);
  }
  __shared__ float red[4][8];
  if ((threadIdx.x & 63) == 0) {
    int wv = threadIdx.x >> 6;
    red[wv][0] = g0; red[wv][1] = g1; red[wv][2] = g2; red[wv][3] = g3;
    red[wv][4] = d0; red[wv][5] = d1; red[wv][6] = d2; red[wv][7] = d3;
  }
  __syncthreads();
  if (threadIdx.x < 4) {
    int nn = threadIdx.x;
    float gg = red[0][nn] + red[1][nn] + red[2][nn] + red[3][nn];
    float dd = red[0][4 + nn] + red[1][4 + nn] + red[2][4 + nn] + red[3][4 + nn];
    float sig = 1.0f / (1.0f + __expf(-gg));
    bias[(b * 4 + nn) * 2048 + s] = sig * dd;
  }
}

// ---------------- bf16 MFMA GEMM: C[M,N] = A[M,K] @ Bt[N,K]^T ----------------
// 128x128 tile, BK=32, 4 waves (2x2), each wave 64x64 (4x4 mfma tiles of 16x16x32)
template <int WRITE_BF16>
__global__ __launch_bounds__(256, 2) void k_gemm_bt(
    const unsigned short* __restrict__ A, const unsigned short* __restrict__ Bt,
    void* __restrict__ Cout, int M, int N, int K) {
  __shared__ __align__(16) unsigned short As[128 * 40]; // pad 32->40: 2-way bank max
  __shared__ __align__(16) unsigned short Bs[128 * 40];
  const int tid = threadIdx.x;
  const int lane = tid & 63, wave = tid >> 6;
  const int quad = lane >> 4, l16 = lane & 15;
  const long bm = (long)blockIdx.y * 128, bn = (long)blockIdx.x * 128;
  const int wm = (wave >> 1) * 64, wn = (wave & 1) * 64;

  const floatx4 fz = {0.f, 0.f, 0.f, 0.f};
  floatx4 acc[4][4];
  #pragma unroll
  for (int i = 0; i < 4; i++)
    #pragma unroll
    for (int j = 0; j < 4; j++) acc[i][j] = fz;

  const int r0 = tid >> 2, c0 = (tid & 3) * 8;
  const unsigned short* Ag = A + (bm + r0) * K + c0;
  const unsigned short* Bg = Bt + (bn + r0) * K + c0;

  for (int kt = 0; kt < K; kt += 32) {
    uintx4 a0 = *reinterpret_cast<const uintx4*>(Ag + kt);
    uintx4 a1 = *reinterpret_cast<const uintx4*>(Ag + (long)64 * K + kt);
    uintx4 b0 = *reinterpret_cast<const uintx4*>(Bg + kt);
    uintx4 b1 = *reinterpret_cast<const uintx4*>(Bg + (long)64 * K + kt);
    __syncthreads();
    *reinterpret_cast<uintx4*>(&As[r0 * 40 + c0]) = a0;
    *reinterpret_cast<uintx4*>(&As[(r0 + 64) * 40 + c0]) = a1;
    *reinterpret_cast<uintx4*>(&Bs[r0 * 40 + c0]) = b0;
    *reinterpret_cast<uintx4*>(&Bs[(r0 + 64) * 40 + c0]) = b1;
    __syncthreads();
    short8 af[4], bf[4];
    #pragma unroll
    for (int i = 0; i < 4; i++)
      af[i] = *reinterpret_cast<const short8*>(&As[(wm + i * 16 + l16) * 40 + quad * 8]);
    #pragma unroll
    for (int j = 0; j < 4; j++)
      bf[j] = *reinterpret_cast<const short8*>(&Bs[(wn + j * 16 + l16) * 40 + quad * 8]);
    #pragma unroll
    for (int i = 0; i < 4; i++)
      #pragma unroll
      for (int j = 0; j < 4; j++)
        acc[i][j] = __builtin_amdgcn_mfma_f32_16x16x32_bf16(af[i], bf[j], acc[i][j], 0, 0, 0);
  }
  // epilogue: C/D layout col=lane&15, row=quad*4+reg
  #pragma unroll
  for (int i = 0; i < 4; i++)
    #pragma unroll
    for (int j = 0; j < 4; j++)
      #pragma unroll
      for (int r = 0; r < 4; r++) {
        const long row = bm + wm + i * 16 + quad * 4 + r;
        const long col = bn + wn + j * 16 + l16;
        const float v = acc[i][j][r];
        if (WRITE_BF16)
          ((unsigned short*)Cout)[row * N + col] = f2bf(v);
        else
          ((float*)Cout)[row * N + col] = v;
      }
}

// ---------------- bf16 transpose of V slice: qkv[.,2560+c] -> vT[(b*512+c)*2048+s] ----------------
__global__ void k_transpose_v(const unsigned short* __restrict__ qkv, unsigned short* __restrict__ vt) {
  __shared__ unsigned short t[32][33];
  int c0 = blockIdx.x * 32, s0 = blockIdx.y * 32, b = blockIdx.z;
  int tx = threadIdx.x & 31, ty = threadIdx.x >> 5;
  #pragma unroll
  for (int r = ty; r < 32; r += 8)
    t[r][tx] = qkv[((long)(b * 2048 + s0 + r)) * 3072 + 2560 + c0 + tx];
  __syncthreads();
  #pragma unroll
  for (int r = ty; r < 32; r += 8)
    vt[((long)(b * 512 + c0 + r)) * 2048 + s0 + tx] = t[tx][r];
}

// ---------------- vmean[b*512 + n*128 + hd] = mean over s of v ----------------
__global__ void k_vmean(const unsigned short* __restrict__ qkv, float* __restrict__ vmean) {
  int b = blockIdx.x >> 2, n = blockIdx.x & 3;
  int hd = threadIdx.x & 127, half = threadIdx.x >> 7;
  float s = 0;
  for (int j = half; j < 2048; j += 2)
    s += bf2f(qkv[((long)(b * 2048 + j)) * 3072 + 2560 + n * 128 + hd]);
  __shared__ float red[256];
  red[threadIdx.x] = s;
  __syncthreads();
  if (threadIdx.x < 128)
    vmean[blockIdx.x * 128 + hd] = (red[hd] + red[128 + hd]) * (1.0f / 2048.0f);
}

// ---------------- flash attention with dynamic mask ----------------
// grid: b(2) x n(4) x g(4) x qt(16) = 512 blocks; 4 waves; wave owns 32 q rows
__global__ __launch_bounds__(256, 2) void k_attn(
    const unsigned short* __restrict__ qkv,  // [4096][3072] (q | k | v)
    const float* __restrict__ biasb,         // [8][2048]
    const unsigned short* __restrict__ vT,   // [1024][2048]
    const float* __restrict__ vmean,         // [1024]
    unsigned short* __restrict__ o)          // [4096][2048]
{
  int idx = blockIdx.x;
  const int qt = idx & 15; idx >>= 4;
  const int g = idx & 3;  idx >>= 2;
  const int n = idx & 3;  idx >>= 2;
  const int b = idx;
  const int tid = threadIdx.x, lane = tid & 63, wave = tid >> 6;
  const int quad = lane >> 4, l16 = lane & 15;
  const int q0 = qt * 128 + wave * 32;

  __shared__ __align__(16) unsigned short Ks[64 * 136];  // [key][hd], pad 128->136
  __shared__ __align__(16) unsigned short Vs[128 * 72];  // [hd][key], pad 64->72
  __shared__ __align__(16) unsigned short Ps[4][32 * 72];// per-wave P, pad 64->72
  __shared__ float Bi[64];

  const float scale = 0.08838834764831845f; // 128^-0.5

  // Q fragments (A-operand): row = q0+mt*16+l16, k = ks*32+quad*8..+8
  short8 qf[2][4];
  {
    const unsigned short* qp = qkv + (long)(b * 2048) * 3072 + (n * 4 + g) * 128;
    #pragma unroll
    for (int mt = 0; mt < 2; mt++)
      #pragma unroll
      for (int ks = 0; ks < 4; ks++)
        qf[mt][ks] = *reinterpret_cast<const short8*>(
            qp + (long)(q0 + mt * 16 + l16) * 3072 + ks * 32 + quad * 8);
  }

  const floatx4 fz = {0.f, 0.f, 0.f, 0.f};
  floatx4 oacc[2][8];
  #pragma unroll
  for (int mt = 0; mt < 2; mt++)
    #pragma unroll
    for (int j = 0; j < 8; j++) oacc[mt][j] = fz;
  float mrow[2][4], lrow[2][4];
  #pragma unroll
  for (int mt = 0; mt < 2; mt++)
    #pragma unroll
    for (int r = 0; r < 4; r++) { mrow[mt][r] = -INFINITY; lrow[mt][r] = 0.0f; }

  const int kend = qt * 128 + 128;
  for (int k0 = 0; k0 < kend; k0 += 64) {
    __syncthreads();  // previous iter LDS reads done
    {
      const unsigned short* kp = qkv + (long)(b * 2048 + k0) * 3072 + 2048 + n * 128;
      #pragma unroll
      for (int it = 0; it < 4; it++) {
        int seg = tid + it * 256;
        int kk = seg >> 4, hdo = (seg & 15) * 8;
        *reinterpret_cast<uintx4*>(&Ks[kk * 136 + hdo]) =
            *reinterpret_cast<const uintx4*>(kp + (long)kk * 3072 + hdo);
      }
      const unsigned short* vp = vT + (long)(b * 512 + n * 128) * 2048 + k0;
      #pragma unroll
      for (int it = 0; it < 4; it++) {
        int seg = tid + it * 256;
        int hd = seg >> 3, ko = (seg & 7) * 8;
        *reinterpret_cast<uintx4*>(&Vs[hd * 72 + ko]) =
            *reinterpret_cast<const uintx4*>(vp + (long)hd * 2048 + ko);
      }
      if (tid < 64) Bi[tid] = biasb[(b * 4 + n) * 2048 + k0 + tid];
    }
    __syncthreads();

    // scores: S = Q @ K^T
    floatx4 sacc[2][4];
    #pragma unroll
    for (int mt = 0; mt < 2; mt++)
      #pragma unroll
      for (int nt = 0; nt < 4; nt++) sacc[mt][nt] = fz;
    #pragma unroll
    for (int ks = 0; ks < 4; ks++) {
      short8 kf[4];
      #pragma unroll
      for (int nt = 0; nt < 4; nt++)
        kf[nt] = *reinterpret_cast<const short8*>(&Ks[(nt * 16 + l16) * 136 + ks * 32 + quad * 8]);
      #pragma unroll
      for (int mt = 0; mt < 2; mt++)
        #pragma unroll
        for (int nt = 0; nt < 4; nt++)
          sacc[mt][nt] = __builtin_amdgcn_mfma_f32_16x16x32_bf16(qf[mt][ks], kf[nt], sacc[mt][nt], 0, 0, 0);
    }

    float bcol[4]; bool alw[4];
    #pragma unroll
    for (int nt = 0; nt < 4; nt++) {
      float bv = Bi[nt * 16 + l16];
      bcol[nt] = bv; alw[nt] = bv > 0.0f;
    }

    // online softmax; C-layout: col(key)=l16, row(q)=quad*4+r
    #pragma unroll
    for (int mt = 0; mt < 2; mt++) {
      #pragma unroll
      for (int r = 0; r < 4; r++) {
        const int qrow = q0 + mt * 16 + quad * 4 + r;
        float mx = -INFINITY;
        #pragma unroll
        for (int nt = 0; nt < 4; nt++) {
          const int key = k0 + nt * 16 + l16;
          float x = sacc[mt][nt][r] * scale + bcol[nt];
          x = (alw[nt] && key <= qrow) ? x : -INFINITY;
          sacc[mt][nt][r] = x;
          mx = fmaxf(mx, x);
        }
        mx = fmaxf(mx, __shfl_xor(mx, 1, 64));
        mx = fmaxf(mx, __shfl_xor(mx, 2, 64));
        mx = fmaxf(mx, __shfl_xor(mx, 4, 64));
        mx = fmaxf(mx, __shfl_xor(mx, 8, 64));
        const float mn = fmaxf(mrow[mt][r], mx);
        const bool empty = (mn == -INFINITY);
        const float alpha = empty ? 1.0f : __expf(mrow[mt][r] - mn);
        float rs = 0.0f;
        #pragma unroll
        for (int nt = 0; nt < 4; nt++) {
          float p = empty ? 0.0f : __expf(sacc[mt][nt][r] - mn);
          sacc[mt][nt][r] = p;
          rs += p;
        }
        rs += __shfl_xor(rs, 1, 64);
        rs += __shfl_xor(rs, 2, 64);
        rs += __shfl_xor(rs, 4, 64);
        rs += __shfl_xor(rs, 8, 64);
        mrow[mt][r] = mn;
        lrow[mt][r] = lrow[mt][r] * alpha + rs;
        #pragma unroll
        for (int j = 0; j < 8; j++) oacc[mt][j][r] *= alpha;
      }
    }

    // P (C-layout) -> LDS -> A-layout
    #pragma unroll
    for (int mt = 0; mt < 2; mt++)
      #pragma unroll
      for (int nt = 0; nt < 4; nt++)
        #pragma unroll
        for (int r = 0; r < 4; r++)
          Ps[wave][(mt * 16 + quad * 4 + r) * 72 + nt * 16 + l16] = f2bf(sacc[mt][nt][r]);
    __syncthreads();

    // O += P @ V
    #pragma unroll
    for (int ks2 = 0; ks2 < 2; ks2++) {
      short8 pf[2];
      #pragma unroll
      for (int mt = 0; mt < 2; mt++)
        pf[mt] = *reinterpret_cast<const short8*>(&Ps[wave][(mt * 16 + l16) * 72 + ks2 * 32 + quad * 8]);
      #pragma unroll
      for (int j = 0; j < 8; j++) {
        short8 vf = *reinterpret_cast<const short8*>(&Vs[(j * 16 + l16) * 72 + ks2 * 32 + quad * 8]);
        #pragma unroll
        for (int mt = 0; mt < 2; mt++)
          oacc[mt][j] = __builtin_amdgcn_mfma_f32_16x16x32_bf16(pf[mt], vf, oacc[mt][j], 0, 0, 0);
      }
    }
  }

  // epilogue
  const long obase = (long)(b * 2048) * 2048 + (n * 4 + g) * 128;
  #pragma unroll
  for (int mt = 0; mt < 2; mt++)
    #pragma unroll
    for (int r = 0; r < 4; r++) {
      const int qrow = q0 + mt * 16 + quad * 4 + r;
      const float l = lrow[mt][r];
      const float inv = (l > 0.0f) ? 1.0f / l : 0.0f;
      #pragma unroll
      for (int j = 0; j < 8; j++) {
        const int hd = j * 16 + l16;
        float v = oacc[mt][j][r] * inv;
        if (l <= 0.0f) v = vmean[(b * 4 + n) * 128 + hd];  // empty row: uniform softmax over ALL keys
        o[obase + (long)qrow * 2048 + hd] = f2bf(v);
      }
    }
}

extern "C" void kernel_launch(void* const* d_in, const int* in_sizes, int n_in,
                              void* d_out, int out_size, void* d_ws, size_t ws_size,
                              hipStream_t stream) {
  const float* hs = (const float*)d_in[0];
  const float* Wq = (const float*)d_in[1];
  const float* Wk = (const float*)d_in[2];
  const float* Wv = (const float*)d_in[3];
  const float* Wg = (const float*)d_in[4];
  const float* Wd = (const float*)d_in[5];
  const float* Wo = (const float*)d_in[6];
  float* out = (float*)d_out;

  char* ws = (char*)d_ws;
  unsigned short* hsb   = (unsigned short*)(ws);               // 16,777,216 B
  unsigned short* Wcomb = (unsigned short*)(ws + 16777216);    // 12,582,912 B  [3072][2048] = Wq^T|Wk^T|Wv^T
  unsigned short* Wot   = (unsigned short*)(ws + 29360128);    //  8,388,608 B
  float*  Wqg   = (float*)(ws + 37748736);                     //     32,768 B
  float*  Wvd   = (float*)(ws + 37781504);                     //     32,768 B
  float*  biasb = (float*)(ws + 37814272);                     //     65,536 B
  unsigned short* qkv = (unsigned short*)(ws + 37879808);      // 25,165,824 B  [4096][3072]
  unsigned short* vT  = (unsigned short*)(ws + 63045632);      //  4,194,304 B
  float*  vmean = (float*)(ws + 67239936);                     //      4,096 B
  unsigned short* ob  = (unsigned short*)(ws + 67244032);      // 16,777,216 B  -> total ~84 MB

  // 1. hs -> bf16
  k_f32_to_bf16<<<2097152 / 256, 256, 0, stream>>>(hs, hsb, 2097152);

  // 2. weight transposes (fp32 -> bf16, B^T layout)
  {
    dim3 g1(2048 / 32, 2048 / 32);
    dim3 g2(512 / 32, 2048 / 32);
    k_transpose_w<<<g1, 256, 0, stream>>>(Wq, Wcomb, 2048, 2048);
    k_transpose_w<<<g2, 256, 0, stream>>>(Wk, Wcomb + (long)2048 * 2048, 2048, 512);
    k_transpose_w<<<g2, 256, 0, stream>>>(Wv, Wcomb + (long)2560 * 2048, 2048, 512);
    k_transpose_w<<<g1, 256, 0, stream>>>(Wo, Wot, 2048, 2048);
  }

  // 3. fused weight products for fp32 gate/delta path
  k_wproj<<<2048, 256, 0, stream>>>(Wq, Wg, Wqg, 2048);
  k_wproj<<<2048, 256, 0, stream>>>(Wv, Wd, Wvd, 512);

  // 4. bias (fp32): sigmoid(hs@Wqg) * (hs@Wvd)
  k_bias<<<4096, 256, 0, stream>>>(hs, Wqg, Wvd, biasb);

  // 5. fused QKV projection GEMM: [4096,3072] = hsb @ Wcomb^T
  {
    dim3 gq(3072 / 128, 4096 / 128);
    k_gemm_bt<1><<<gq, 256, 0, stream>>>(hsb, Wcomb, qkv, 4096, 3072, 2048);
  }

  // 6. V transpose (for PV B-operand layout)
  {
    dim3 gv(16, 64, 2);
    k_transpose_v<<<gv, 256, 0, stream>>>(qkv, vT);
  }

  // 7. per-(b,n) mean of V (empty-row fallback)
  k_vmean<<<8, 256, 0, stream>>>(qkv, vmean);

  // 8. flash attention with dynamic mask
  k_attn<<<512, 256, 0, stream>>>(qkv, biasb, vT, vmean, ob);

  // 9. output projection: out = ob @ Wo  (fp32 out)
  {
    dim3 go(2048 / 128, 4096 / 128);
    k_gemm_bt<0><<<go, 256, 0, stream>>>(ob, Wot, out, 4096, 2048, 2048);
  }
}

// Round 2
// 488.310 us; speedup vs baseline: 1.5342x; 1.5342x over previous
//
#include <hip/hip_runtime.h>
#include <hip/hip_bf16.h>
#include <cmath>
#include <cstdint>

typedef __attribute__((ext_vector_type(8))) short short8;
typedef __attribute__((ext_vector_type(4))) float floatx4;
typedef __attribute__((ext_vector_type(4))) unsigned int uintx4;

typedef const __attribute__((address_space(1))) unsigned int* gas_p;
typedef __attribute__((address_space(3))) unsigned int* las_p;

__device__ inline unsigned short f2bf(float f) {
  unsigned int u = __builtin_bit_cast(unsigned int, f);
  unsigned int r = (u + 0x7FFFu + ((u >> 16) & 1u)) >> 16;
  return (unsigned short)r;
}
__device__ inline float bf2f(unsigned short h) {
  unsigned int u = ((unsigned int)h) << 16;
  return __builtin_bit_cast(float, u);
}

// ---------------- elementwise fp32 -> bf16 (float4 loads) ----------------
__global__ void k_f32_to_bf16(const float* __restrict__ in, unsigned short* __restrict__ out, int n4) {
  int i = blockIdx.x * 256 + threadIdx.x;
  if (i >= n4) return;
  float4 v = reinterpret_cast<const float4*>(in)[i];
  uint2 o;
  o.x = (unsigned)f2bf(v.x) | ((unsigned)f2bf(v.y) << 16);
  o.y = (unsigned)f2bf(v.z) | ((unsigned)f2bf(v.w) << 16);
  reinterpret_cast<uint2*>(out)[i] = o;
}

// ---------------- transpose + convert: fp32 [K][N] -> bf16 [N][K] ----------------
__global__ void k_transpose_w(const float* __restrict__ in, unsigned short* __restrict__ out, int K, int N) {
  __shared__ float t[32][33];
  int n0 = blockIdx.x * 32, k0 = blockIdx.y * 32;
  int tx = threadIdx.x & 31, ty = threadIdx.x >> 5; // 256 threads: ty 0..7
  #pragma unroll
  for (int r = ty; r < 32; r += 8)
    t[r][tx] = in[(long)(k0 + r) * N + n0 + tx];
  __syncthreads();
  #pragma unroll
  for (int r = ty; r < 32; r += 8)
    out[(long)(n0 + r) * K + k0 + tx] = f2bf(t[tx][r]);
}

// ---------------- small fp32 GEMM: out[d][0..3] = W[d,:] @ Ws (Kw x 4) ----------------
__global__ void k_wproj(const float* __restrict__ W, const float* __restrict__ Ws,
                        float* __restrict__ out, int Kw) {
  int d = blockIdx.x;
  float a0 = 0, a1 = 0, a2 = 0, a3 = 0;
  for (int j = threadIdx.x; j < Kw; j += 256) {
    float w = W[(long)d * Kw + j];
    float4 g = reinterpret_cast<const float4*>(Ws)[j];
    a0 += w * g.x; a1 += w * g.y; a2 += w * g.z; a3 += w * g.w;
  }
  #pragma unroll
  for (int off = 1; off < 64; off <<= 1) {
    a0 += __shfl_xor(a0, off, 64); a1 += __shfl_xor(a1, off, 64);
    a2 += __shfl_xor(a2, off, 64); a3 += __shfl_xor(a3, off, 64);
  }
  __shared__ float red[4][4];
  if ((threadIdx.x & 63) == 0) {
    int wv = threadIdx.x >> 6;
    red[wv][0] = a0; red[wv][1] = a1; red[wv][2] = a2; red[wv][3] = a3;
  }
  __syncthreads();
  if (threadIdx.x < 4) {
    int nn = threadIdx.x;
    out[d * 4 + nn] = red[0][nn] + red[1][nn] + red[2][nn] + red[3][nn];
  }
}

// ---------------- bias: fp32 gate/delta -> bias[(b*4+n)*S + s] ----------------
__global__ void k_bias(const float* __restrict__ hs, const float* __restrict__ Wqg,
                       const float* __restrict__ Wvd, float* __restrict__ bias) {
  int row = blockIdx.x;           // b*2048 + s
  int b = row >> 11, s = row & 2047;
  float g0 = 0, g1 = 0, g2 = 0, g3 = 0, d0 = 0, d1 = 0, d2 = 0, d3 = 0;
  const float* h = hs + (long)row * 2048;
  for (int j = threadIdx.x; j < 2048; j += 256) {
    float x = h[j];
    float4 a = reinterpret_cast<const float4*>(Wqg)[j];
    float4 c = reinterpret_cast<const float4*>(Wvd)[j];
    g0 += x * a.x; g1 += x * a.y; g2 += x * a.z; g3 += x * a.w;
    d0 += x * c.x; d1 += x * c.y; d2 += x * c.z; d3 += x * c.w;
  }
  #pragma unroll
  for (int off = 1; off < 64; off <<= 1) {
    g0 += __shfl_xor(g0, off, 64); g1 += __shfl_xor(g1, off, 64);
    g2 += __shfl_xor(g2, off, 64); g3 += __shfl_xor(g3, off, 64);
    d0 += __shfl_xor(d0, off, 64); d1 += __shfl_xor(d1, off, 64);
    d2 += __shfl_xor(d2, off, 64); d3 += __shfl_xor(d3, off, 64);
  }
  __shared__ float red[4][8];
  if ((threadIdx.x & 63) == 0) {
    int wv = threadIdx.x >> 6;
    red[wv][0] = g0; red[wv][1] = g1; red[wv][2] = g2; red[wv][3] = g3;
    red[wv][4] = d0; red[wv][5] = d1; red[wv][6] = d2; red[wv][7] = d3;
  }
  __syncthreads();
  if (threadIdx.x < 4) {
    int nn = threadIdx.x;
    float gg = red[0][nn] + red[1][nn] + red[2][nn] + red[3][nn];
    float dd = red[0][4 + nn] + red[1][4 + nn] + red[2][4 + nn] + red[3][4 + nn];
    float sig = 1.0f / (1.0f + __expf(-gg));
    bias[(b * 4 + nn) * 2048 + s] = sig * dd;
  }
}

// ---------------- bf16 MFMA GEMM: C[M,N] = A[M,K] @ Bt[N,K]^T ----------------
// m97 structure: 128x128 tile, BK=32, async global_load_lds width=16, unpadded
// LDS stride 32 ushort (64 B -> 2-way bank aliasing, free per m136).
template <int WRITE_BF16>
__global__ __launch_bounds__(256, 2) void k_gemm_bt(
    const unsigned short* __restrict__ A, const unsigned short* __restrict__ Bt,
    void* __restrict__ Cout, int M, int N, int K) {
  __shared__ __align__(16) unsigned short As[128 * 32];
  __shared__ __align__(16) unsigned short Bs[128 * 32];
  const int tid = threadIdx.x;
  const int lane = tid & 63, wave = tid >> 6;
  const int quad = lane >> 4, l16 = lane & 15;
  const long bm = (long)blockIdx.y * 128, bn = (long)blockIdx.x * 128;
  const int wm = (wave >> 1) * 64, wn = (wave & 1) * 64;

  const floatx4 fz = {0.f, 0.f, 0.f, 0.f};
  floatx4 acc[4][4];
  #pragma unroll
  for (int i = 0; i < 4; i++)
    #pragma unroll
    for (int j = 0; j < 4; j++) acc[i][j] = fz;

  // staging map: lane l of wave w covers row w*16 + l/4 (+64), cols (l%4)*8..+8
  // LDS dest = wave-uniform base + lane*16 B == ((l/4)*32 + (l%4)*8) ushorts -> [row][32] layout
  const int r0 = tid >> 2, c0 = (tid & 3) * 8;
  const unsigned short* Ag = A + (bm + r0) * K + c0;
  const unsigned short* Bg = Bt + (bn + r0) * K + c0;
  unsigned short* AsW0 = As + (wave * 16) * 32;
  unsigned short* AsW1 = As + (wave * 16 + 64) * 32;
  unsigned short* BsW0 = Bs + (wave * 16) * 32;
  unsigned short* BsW1 = Bs + (wave * 16 + 64) * 32;

  for (int kt = 0; kt < K; kt += 32) {
    __syncthreads();  // all waves done reading previous tile
    __builtin_amdgcn_global_load_lds((gas_p)(const void*)(Ag + kt),
                                     (las_p)(void*)AsW0, 16, 0, 0);
    __builtin_amdgcn_global_load_lds((gas_p)(const void*)(Ag + (long)64 * K + kt),
                                     (las_p)(void*)AsW1, 16, 0, 0);
    __builtin_amdgcn_global_load_lds((gas_p)(const void*)(Bg + kt),
                                     (las_p)(void*)BsW0, 16, 0, 0);
    __builtin_amdgcn_global_load_lds((gas_p)(const void*)(Bg + (long)64 * K + kt),
                                     (las_p)(void*)BsW1, 16, 0, 0);
    __syncthreads();  // drains vmcnt -> tiles visible
    short8 af[4], bf[4];
    #pragma unroll
    for (int i = 0; i < 4; i++)
      af[i] = *reinterpret_cast<const short8*>(&As[(wm + i * 16 + l16) * 32 + quad * 8]);
    #pragma unroll
    for (int j = 0; j < 4; j++)
      bf[j] = *reinterpret_cast<const short8*>(&Bs[(wn + j * 16 + l16) * 32 + quad * 8]);
    #pragma unroll
    for (int i = 0; i < 4; i++)
      #pragma unroll
      for (int j = 0; j < 4; j++)
        acc[i][j] = __builtin_amdgcn_mfma_f32_16x16x32_bf16(af[i], bf[j], acc[i][j], 0, 0, 0);
  }
  // epilogue: C/D layout col=lane&15, row=quad*4+reg
  #pragma unroll
  for (int i = 0; i < 4; i++)
    #pragma unroll
    for (int j = 0; j < 4; j++)
      #pragma unroll
      for (int r = 0; r < 4; r++) {
        const long row = bm + wm + i * 16 + quad * 4 + r;
        const long col = bn + wn + j * 16 + l16;
        const float v = acc[i][j][r];
        if (WRITE_BF16)
          ((unsigned short*)Cout)[row * N + col] = f2bf(v);
        else
          ((float*)Cout)[row * N + col] = v;
      }
}

// ---------------- bf16 transpose of V slice: qkv[.,2560+c] -> vT[(b*512+c)*2048+s] ----------------
__global__ void k_transpose_v(const unsigned short* __restrict__ qkv, unsigned short* __restrict__ vt) {
  __shared__ unsigned short t[32][33];
  int c0 = blockIdx.x * 32, s0 = blockIdx.y * 32, b = blockIdx.z;
  int tx = threadIdx.x & 31, ty = threadIdx.x >> 5;
  #pragma unroll
  for (int r = ty; r < 32; r += 8)
    t[r][tx] = qkv[((long)(b * 2048 + s0 + r)) * 3072 + 2560 + c0 + tx];
  __syncthreads();
  #pragma unroll
  for (int r = ty; r < 32; r += 8)
    vt[((long)(b * 512 + c0 + r)) * 2048 + s0 + tx] = t[tx][r];
}

// ---------------- vmean from vT rows (coalesced): vmean[row] = mean_s vT[row][s] ----------------
// vT row index b*512 + n*128 + hd == vmean index (b*4+n)*128 + hd used in k_attn.
__global__ void k_vmean2(const unsigned short* __restrict__ vT, float* __restrict__ vmean) {
  const int row = blockIdx.x;  // 1024
  const int tid = threadIdx.x, lane = tid & 63, wave = tid >> 6;
  uintx4 v = reinterpret_cast<const uintx4*>(vT + (long)row * 2048)[tid]; // 256*8 bf16 = 2048
  float s = 0.f;
  #pragma unroll
  for (int i = 0; i < 4; i++) {
    unsigned u = v[i];
    s += bf2f((unsigned short)(u & 0xffff)) + bf2f((unsigned short)(u >> 16));
  }
  #pragma unroll
  for (int off = 1; off < 64; off <<= 1) s += __shfl_xor(s, off, 64);
  __shared__ float red[4];
  if (lane == 0) red[wave] = s;
  __syncthreads();
  if (tid == 0) vmean[row] = (red[0] + red[1] + red[2] + red[3]) * (1.0f / 2048.0f);
}

// ---------------- flash attention with dynamic mask ----------------
// grid: b(2) x n(4) x g(4) x qt(16) = 512 blocks; 4 waves; wave owns 32 q rows
__global__ __launch_bounds__(256, 2) void k_attn(
    const unsigned short* __restrict__ qkv,  // [4096][3072] (q | k | v)
    const float* __restrict__ biasb,         // [8][2048]
    const unsigned short* __restrict__ vT,   // [1024][2048]
    const float* __restrict__ vmean,         // [1024]
    unsigned short* __restrict__ o)          // [4096][2048]
{
  int idx = blockIdx.x;
  const int qt = idx & 15; idx >>= 4;
  const int g = idx & 3;  idx >>= 2;
  const int n = idx & 3;  idx >>= 2;
  const int b = idx;
  const int tid = threadIdx.x, lane = tid & 63, wave = tid >> 6;
  const int quad = lane >> 4, l16 = lane & 15;
  const int q0 = qt * 128 + wave * 32;

  __shared__ __align__(16) unsigned short Ks[64 * 136];  // [key][hd], pad 128->136
  __shared__ __align__(16) unsigned short Vs[128 * 72];  // [hd][key], pad 64->72
  __shared__ __align__(16) unsigned short Ps[4][32 * 72];// per-wave P, pad 64->72
  __shared__ float Bi[64];

  const float scale = 0.08838834764831845f; // 128^-0.5

  // Q fragments (A-operand): row = q0+mt*16+l16, k = ks*32+quad*8..+8
  short8 qf[2][4];
  {
    const unsigned short* qp = qkv + (long)(b * 2048) * 3072 + (n * 4 + g) * 128;
    #pragma unroll
    for (int mt = 0; mt < 2; mt++)
      #pragma unroll
      for (int ks = 0; ks < 4; ks++)
        qf[mt][ks] = *reinterpret_cast<const short8*>(
            qp + (long)(q0 + mt * 16 + l16) * 3072 + ks * 32 + quad * 8);
  }

  const floatx4 fz = {0.f, 0.f, 0.f, 0.f};
  floatx4 oacc[2][8];
  #pragma unroll
  for (int mt = 0; mt < 2; mt++)
    #pragma unroll
    for (int j = 0; j < 8; j++) oacc[mt][j] = fz;
  float mrow[2][4], lrow[2][4];
  #pragma unroll
  for (int mt = 0; mt < 2; mt++)
    #pragma unroll
    for (int r = 0; r < 4; r++) { mrow[mt][r] = -INFINITY; lrow[mt][r] = 0.0f; }

  const int kend = qt * 128 + 128;
  for (int k0 = 0; k0 < kend; k0 += 64) {
    __syncthreads();  // previous iter LDS reads done
    {
      const unsigned short* kp = qkv + (long)(b * 2048 + k0) * 3072 + 2048 + n * 128;
      #pragma unroll
      for (int it = 0; it < 4; it++) {
        int seg = tid + it * 256;
        int kk = seg >> 4, hdo = (seg & 15) * 8;
        *reinterpret_cast<uintx4*>(&Ks[kk * 136 + hdo]) =
            *reinterpret_cast<const uintx4*>(kp + (long)kk * 3072 + hdo);
      }
      const unsigned short* vp = vT + (long)(b * 512 + n * 128) * 2048 + k0;
      #pragma unroll
      for (int it = 0; it < 4; it++) {
        int seg = tid + it * 256;
        int hd = seg >> 3, ko = (seg & 7) * 8;
        *reinterpret_cast<uintx4*>(&Vs[hd * 72 + ko]) =
            *reinterpret_cast<const uintx4*>(vp + (long)hd * 2048 + ko);
      }
      if (tid < 64) Bi[tid] = biasb[(b * 4 + n) * 2048 + k0 + tid];
    }
    __syncthreads();

    // scores: S = Q @ K^T
    floatx4 sacc[2][4];
    #pragma unroll
    for (int mt = 0; mt < 2; mt++)
      #pragma unroll
      for (int nt = 0; nt < 4; nt++) sacc[mt][nt] = fz;
    #pragma unroll
    for (int ks = 0; ks < 4; ks++) {
      short8 kf[4];
      #pragma unroll
      for (int nt = 0; nt < 4; nt++)
        kf[nt] = *reinterpret_cast<const short8*>(&Ks[(nt * 16 + l16) * 136 + ks * 32 + quad * 8]);
      #pragma unroll
      for (int mt = 0; mt < 2; mt++)
        #pragma unroll
        for (int nt = 0; nt < 4; nt++)
          sacc[mt][nt] = __builtin_amdgcn_mfma_f32_16x16x32_bf16(qf[mt][ks], kf[nt], sacc[mt][nt], 0, 0, 0);
    }

    float bcol[4]; bool alw[4];
    #pragma unroll
    for (int nt = 0; nt < 4; nt++) {
      float bv = Bi[nt * 16 + l16];
      bcol[nt] = bv; alw[nt] = bv > 0.0f;
    }

    // online softmax; C-layout: col(key)=l16, row(q)=quad*4+r
    #pragma unroll
    for (int mt = 0; mt < 2; mt++) {
      #pragma unroll
      for (int r = 0; r < 4; r++) {
        const int qrow = q0 + mt * 16 + quad * 4 + r;
        float mx = -INFINITY;
        #pragma unroll
        for (int nt = 0; nt < 4; nt++) {
          const int key = k0 + nt * 16 + l16;
          float x = sacc[mt][nt][r] * scale + bcol[nt];
          x = (alw[nt] && key <= qrow) ? x : -INFINITY;
          sacc[mt][nt][r] = x;
          mx = fmaxf(mx, x);
        }
        mx = fmaxf(mx, __shfl_xor(mx, 1, 64));
        mx = fmaxf(mx, __shfl_xor(mx, 2, 64));
        mx = fmaxf(mx, __shfl_xor(mx, 4, 64));
        mx = fmaxf(mx, __shfl_xor(mx, 8, 64));
        const float mn = fmaxf(mrow[mt][r], mx);
        const bool empty = (mn == -INFINITY);
        const float alpha = empty ? 1.0f : __expf(mrow[mt][r] - mn);
        float rs = 0.0f;
        #pragma unroll
        for (int nt = 0; nt < 4; nt++) {
          float p = empty ? 0.0f : __expf(sacc[mt][nt][r] - mn);
          sacc[mt][nt][r] = p;
          rs += p;
        }
        rs += __shfl_xor(rs, 1, 64);
        rs += __shfl_xor(rs, 2, 64);
        rs += __shfl_xor(rs, 4, 64);
        rs += __shfl_xor(rs, 8, 64);
        mrow[mt][r] = mn;
        lrow[mt][r] = lrow[mt][r] * alpha + rs;
        #pragma unroll
        for (int j = 0; j < 8; j++) oacc[mt][j][r] *= alpha;
      }
    }

    // P (C-layout) -> LDS -> A-layout
    #pragma unroll
    for (int mt = 0; mt < 2; mt++)
      #pragma unroll
      for (int nt = 0; nt < 4; nt++)
        #pragma unroll
        for (int r = 0; r < 4; r++)
          Ps[wave][(mt * 16 + quad * 4 + r) * 72 + nt * 16 + l16] = f2bf(sacc[mt][nt][r]);
    __syncthreads();

    // O += P @ V
    #pragma unroll
    for (int ks2 = 0; ks2 < 2; ks2++) {
      short8 pf[2];
      #pragma unroll
      for (int mt = 0; mt < 2; mt++)
        pf[mt] = *reinterpret_cast<const short8*>(&Ps[wave][(mt * 16 + l16) * 72 + ks2 * 32 + quad * 8]);
      #pragma unroll
      for (int j = 0; j < 8; j++) {
        short8 vf = *reinterpret_cast<const short8*>(&Vs[(j * 16 + l16) * 72 + ks2 * 32 + quad * 8]);
        #pragma unroll
        for (int mt = 0; mt < 2; mt++)
          oacc[mt][j] = __builtin_amdgcn_mfma_f32_16x16x32_bf16(pf[mt], vf, oacc[mt][j], 0, 0, 0);
      }
    }
  }

  // epilogue
  const long obase = (long)(b * 2048) * 2048 + (n * 4 + g) * 128;
  #pragma unroll
  for (int mt = 0; mt < 2; mt++)
    #pragma unroll
    for (int r = 0; r < 4; r++) {
      const int qrow = q0 + mt * 16 + quad * 4 + r;
      const float l = lrow[mt][r];
      const float inv = (l > 0.0f) ? 1.0f / l : 0.0f;
      #pragma unroll
      for (int j = 0; j < 8; j++) {
        const int hd = j * 16 + l16;
        float v = oacc[mt][j][r] * inv;
        if (l <= 0.0f) v = vmean[(b * 4 + n) * 128 + hd];  // empty row: uniform softmax over ALL keys
        o[obase + (long)qrow * 2048 + hd] = f2bf(v);
      }
    }
}

extern "C" void kernel_launch(void* const* d_in, const int* in_sizes, int n_in,
                              void* d_out, int out_size, void* d_ws, size_t ws_size,
                              hipStream_t stream) {
  const float* hs = (const float*)d_in[0];
  const float* Wq = (const float*)d_in[1];
  const float* Wk = (const float*)d_in[2];
  const float* Wv = (const float*)d_in[3];
  const float* Wg = (const float*)d_in[4];
  const float* Wd = (const float*)d_in[5];
  const float* Wo = (const float*)d_in[6];
  float* out = (float*)d_out;

  char* ws = (char*)d_ws;
  unsigned short* hsb   = (unsigned short*)(ws);               // 16,777,216 B
  unsigned short* Wcomb = (unsigned short*)(ws + 16777216);    // 12,582,912 B  [3072][2048] = Wq^T|Wk^T|Wv^T
  unsigned short* Wot   = (unsigned short*)(ws + 29360128);    //  8,388,608 B
  float*  Wqg   = (float*)(ws + 37748736);                     //     32,768 B
  float*  Wvd   = (float*)(ws + 37781504);                     //     32,768 B
  float*  biasb = (float*)(ws + 37814272);                     //     65,536 B
  unsigned short* qkv = (unsigned short*)(ws + 37879808);      // 25,165,824 B  [4096][3072]
  unsigned short* vT  = (unsigned short*)(ws + 63045632);      //  4,194,304 B
  float*  vmean = (float*)(ws + 67239936);                     //      4,096 B
  unsigned short* ob  = (unsigned short*)(ws + 67244032);      // 16,777,216 B  -> total ~84 MB

  // 1. hs -> bf16
  k_f32_to_bf16<<<2097152 / 256, 256, 0, stream>>>(hs, hsb, 2097152);

  // 2. weight transposes (fp32 -> bf16, B^T layout)
  {
    dim3 g1(2048 / 32, 2048 / 32);
    dim3 g2(512 / 32, 2048 / 32);
    k_transpose_w<<<g1, 256, 0, stream>>>(Wq, Wcomb, 2048, 2048);
    k_transpose_w<<<g2, 256, 0, stream>>>(Wk, Wcomb + (long)2048 * 2048, 2048, 512);
    k_transpose_w<<<g2, 256, 0, stream>>>(Wv, Wcomb + (long)2560 * 2048, 2048, 512);
    k_transpose_w<<<g1, 256, 0, stream>>>(Wo, Wot, 2048, 2048);
  }

  // 3. fused weight products for fp32 gate/delta path
  k_wproj<<<2048, 256, 0, stream>>>(Wq, Wg, Wqg, 2048);
  k_wproj<<<2048, 256, 0, stream>>>(Wv, Wd, Wvd, 512);

  // 4. bias (fp32): sigmoid(hs@Wqg) * (hs@Wvd)
  k_bias<<<4096, 256, 0, stream>>>(hs, Wqg, Wvd, biasb);

  // 5. fused QKV projection GEMM: [4096,3072] = hsb @ Wcomb^T
  {
    dim3 gq(3072 / 128, 4096 / 128);
    k_gemm_bt<1><<<gq, 256, 0, stream>>>(hsb, Wcomb, qkv, 4096, 3072, 2048);
  }

  // 6. V transpose (for PV B-operand layout)
  {
    dim3 gv(16, 64, 2);
    k_transpose_v<<<gv, 256, 0, stream>>>(qkv, vT);
  }

  // 7. per-(b,n) mean of V from vT (coalesced) — replaces the 253 µs strided k_vmean
  k_vmean2<<<1024, 256, 0, stream>>>(vT, vmean);

  // 8. flash attention with dynamic mask
  k_attn<<<512, 256, 0, stream>>>(qkv, biasb, vT, vmean, ob);

  // 9. output projection: out = ob @ Wo  (fp32 out)
  {
    dim3 go(2048 / 128, 4096 / 128);
    k_gemm_bt<0><<<go, 256, 0, stream>>>(ob, Wot, out, 4096, 2048, 2048);
  }
}